// Round 5
// baseline (380.602 us; speedup 1.0000x reference)
//
#include <hip/hip_runtime.h>

#define LOSS_OFF 8388608
#define IDX_OFF  8388609

// ws layout (bytes)
#define WS_SEE   0          // float[1024]
#define WS_SXX   4096       // float[32768]           -> ends 135168
#define WS_KEY   135168     // u64[32768] packed (m,idx) -> ends 397312
#define WS_LOSS  397312     // double

#define FLT_BIG  3.402823466e+38f

// numpy pairwise_sum of 256 squared elements, bit-exact (see round-2 notes).
__device__ __forceinline__ float np_sumsq256(const float* __restrict__ p, int stride) {
    float s[2];
#pragma unroll
    for (int half = 0; half < 2; half++) {
        const float* a = p + half * 128 * stride;
        float r[8];
#pragma unroll
        for (int l = 0; l < 8; l++) {
            float v = a[l * stride];
            float sq = v * v;
            asm volatile("" : "+v"(sq));   // forbid fma contraction into the add chain
            r[l] = sq;
        }
#pragma unroll
        for (int i = 8; i < 128; i += 8) {
#pragma unroll
            for (int l = 0; l < 8; l++) {
                float v = a[(i + l) * stride];
                float sq = v * v;
                asm volatile("" : "+v"(sq));
                r[l] = r[l] + sq;
            }
        }
        s[half] = ((r[0] + r[1]) + (r[2] + r[3])) + ((r[4] + r[5]) + (r[6] + r[7]));
    }
    return s[0] + s[1];
}

__device__ __forceinline__ unsigned int f32_sortable(float m) {
    unsigned int u = __float_as_uint(m);
    return u ^ (((unsigned int)((int)u >> 31)) | 0x80000000u);
}

// ---------------- k0: codebook ||e||^2 (np semantics) + init ----------------
__global__ __launch_bounds__(256) void k0_see(const float* __restrict__ emb,
                                              float* __restrict__ see,
                                              double* __restrict__ loss) {
    const int k = blockIdx.x * 256 + threadIdx.x;   // grid 4 x 256
    see[k] = np_sumsq256(emb + (size_t)k * 256, 1);
    if (k == 0) { *loss = 0.0; }
}

// ---------------- k_sxx: per-row ||x||^2 (np semantics) + key init ----------------
__global__ __launch_bounds__(64) void k_sxx(const float* __restrict__ x,
                                            float* __restrict__ sxx,
                                            unsigned long long* __restrict__ key) {
    const int n = blockIdx.x * 64 + threadIdx.x;    // grid 512 x 64
    const int b = n >> 10, hw = n & 1023;
    sxx[n] = np_sumsq256(x + (size_t)b * 262144 + hw, 1024);
    key[n] = ~0ull;
}

// ---------------- k1: fp32 GEMM distances + np-rounded argmin ----------------
// grid 1024 (= 512 row-blocks x 2 K-halves), block 256 threads (4 waves).
// Tile: 64 rows x 512 codes (2 kt-tiles of 256), c-chunks of 16.
// LDS 21.5 KB + VGPR<=128 -> target 4 blocks/CU (16 waves) for barrier overlap.
// dot is a sequential fp32 FMA chain over c=0..255 (bit-matches np reference).
// Bank behavior: Xs rows = 64 floats -> a-reads 2-way (free, m136); Es b128
// reads 2-way + 8-lane broadcast; staging writes conflict-free. No swizzle.
__global__ __launch_bounds__(256, 4) void k1_dist(const float* __restrict__ x,
                                                  const float* __restrict__ emb,
                                                  const float* __restrict__ see_g,
                                                  const float* __restrict__ sxx_g,
                                                  unsigned long long* __restrict__ key) {
    __shared__ float smem[5376];
    float* Xs   = smem;             // [16 c][64 r]
    float* Es   = smem + 1024;      // [16 c][256 k]
    float* sees = smem + 5120;      // [256]

    const int t    = threadIdx.x;
    const int blk  = blockIdx.x;
    const int rb   = blk >> 1;      // row block 0..511 (64 rows each)
    const int half = blk & 1;       // K half
    const int b    = rb >> 4;
    const int rem0 = (rb & 15) << 6;
    const float* xb = x + (size_t)b * 262144 + rem0;

    const int tr = t & 7;         // rows 8*tr .. 8*tr+7
    const int tk = t >> 3;        // codes 8*tk .. 8*tk+7 within 256-code tile

    float sx[8];
#pragma unroll
    for (int i = 0; i < 8; i++) sx[i] = sxx_g[rb * 64 + 8 * tr + i];

    float bm1[8]; int bi1[8];
#pragma unroll
    for (int i = 0; i < 8; i++) { bm1[i] = FLT_BIG; bi1[i] = 0; }

    // staging thread mapping
    const int sc  = t >> 4;         // c within chunk (0..15) for Xs
    const int sr4 = (t & 15) << 2;  // 4-row group for Xs
    const int ke  = t & 63;         // code lane for Es
    const int cq  = (t >> 6) << 2;  // c-quad for Es

    for (int q = 0; q < 2; q++) {
        const int kt = half * 2 + q;
        float acc[8][8];
#pragma unroll
        for (int i = 0; i < 8; i++)
#pragma unroll
            for (int j = 0; j < 8; j++) acc[i][j] = 0.f;

        for (int cc = 0; cc < 16; cc++) {
            const int cb = cc * 16;
            __syncthreads();                       // prior chunk's reads done
            if (cc == 0) sees[t] = see_g[kt * 256 + t];
            // stage X^T chunk: [16 c][64 r]
            {
                const float4 xv = *(const float4*)(xb + (size_t)(cb + sc) * 1024 + sr4);
                *(float4*)(Xs + sc * 64 + sr4) = xv;
            }
            // stage E^T chunk: [16 c][256 k]
#pragma unroll
            for (int kk = 0; kk < 4; kk++) {
                const int k = kk * 64 + ke;
                const float4 ev = *(const float4*)(emb + (size_t)(kt * 256 + k) * 256 + cb + cq);
                Es[(cq + 0) * 256 + k] = ev.x;
                Es[(cq + 1) * 256 + k] = ev.y;
                Es[(cq + 2) * 256 + k] = ev.z;
                Es[(cq + 3) * 256 + k] = ev.w;
            }
            __syncthreads();
            // sequential fp32 FMA chain over c (bit-matches np sequential dot)
#pragma unroll 4
            for (int c = 0; c < 16; c++) {
                float a[8], bv[8];
                *(float4*)&a[0]  = *(const float4*)(Xs + c * 64 + 8 * tr);
                *(float4*)&a[4]  = *(const float4*)(Xs + c * 64 + 8 * tr + 4);
                *(float4*)&bv[0] = *(const float4*)(Es + c * 256 + 8 * tk);
                *(float4*)&bv[4] = *(const float4*)(Es + c * 256 + 8 * tk + 4);
#pragma unroll
                for (int i = 0; i < 8; i++)
#pragma unroll
                    for (int j = 0; j < 8; j++)
                        acc[i][j] = fmaf(a[i], bv[j], acc[i][j]);
            }
        }
        // np-rounded distance: q = fl(fl(sxx - 2*dot) + see)   (2*dot exact)
#pragma unroll
        for (int i = 0; i < 8; i++) {
#pragma unroll
            for (int j = 0; j < 8; j++) {
                const int k = kt * 256 + 8 * tk + j;
                const float t1 = fmaf(-2.f, acc[i][j], sx[i]);
                const float qd = t1 + sees[8 * tk + j];
                if (qd < bm1[i]) { bm1[i] = qd; bi1[i] = k; }   // ascending k: strict < keeps first
            }
        }
    }

    // cross-thread reduction (32 tk-groups per row), then cross-block atomic merge
    __syncthreads();
    float* rm1 = smem;                 // [64][33] floats
    int*   ri1 = (int*)(smem + 2112);  // [64][33] ints
#pragma unroll
    for (int i = 0; i < 8; i++) {
        const int r = 8 * tr + i;
        rm1[r * 33 + tk] = bm1[i];
        ri1[r * 33 + tk] = bi1[i];
    }
    __syncthreads();
    if (t < 64) {
        const int r = t;
        float M1 = FLT_BIG; int I1 = 0x7fffffff;
        for (int g = 0; g < 32; g++) {             // ascending g = ascending k
            const float m1 = rm1[r * 33 + g];
            const int   i1 = ri1[r * 33 + g];
            if (m1 < M1)       { M1 = m1; I1 = i1; }
            else if (m1 == M1) { I1 = min(I1, i1); }
        }
        const unsigned long long pk =
            ((unsigned long long)f32_sortable(M1) << 32) | (unsigned int)I1;
        atomicMin(&key[rb * 64 + r], pk);
    }
}

// ---------------- k3: gather quantized + loss partials + indices ----------------
__global__ __launch_bounds__(256) void k3_out(const float* __restrict__ x,
                                              const float* __restrict__ emb,
                                              const unsigned long long* __restrict__ key,
                                              float* __restrict__ dout,
                                              double* __restrict__ loss) {
    __shared__ float elds[32][257];
    __shared__ int   idxs[32];
    __shared__ float red[256];
    const int t  = threadIdx.x;
    const int bh = blockIdx.x;
    const int b = bh >> 5, h = bh & 31;
    if (t < 32) idxs[t] = (int)(key[(bh << 5) + t] & 0xffffffffull);
    __syncthreads();
    for (int r = 0; r < 32; r++) elds[r][t] = emb[(size_t)idxs[r] * 256 + t];
    __syncthreads();
    const int w = t & 31, cg = t >> 5;
    const size_t base = (size_t)b * 262144 + (size_t)(h * 32 + w);
    float acc = 0.f;
#pragma unroll 4
    for (int s = 0; s < 32; s++) {
        const int c = (cg << 5) + s;
        const float q  = elds[w][c];
        const float xv = x[base + (size_t)c * 1024];
        dout[base + (size_t)c * 1024] = q;
        const float d = q - xv;
        acc = fmaf(d, d, acc);
    }
    red[t] = acc;
    __syncthreads();
    for (int s = 128; s > 0; s >>= 1) {
        if (t < s) red[t] += red[t + s];
        __syncthreads();
    }
    if (t == 0) atomicAdd(loss, (double)red[0]);
    if (t < 32) dout[IDX_OFF + (bh << 5) + t] = (float)idxs[t];
}

// ---------------- k4: finalize loss ----------------
__global__ void k4_fin(const double* __restrict__ loss, float* __restrict__ dout) {
    dout[LOSS_OFF] = (float)(1.25 * (*loss) / 8388608.0);
}

extern "C" void kernel_launch(void* const* d_in, const int* in_sizes, int n_in,
                              void* d_out, int out_size, void* d_ws, size_t ws_size,
                              hipStream_t stream) {
    const float* x   = (const float*)d_in[0];
    const float* emb = (const float*)d_in[1];
    float* dout = (float*)d_out;
    char* ws = (char*)d_ws;
    float*  see  = (float*)(ws + WS_SEE);
    float*  sxx  = (float*)(ws + WS_SXX);
    unsigned long long* key = (unsigned long long*)(ws + WS_KEY);
    double* loss = (double*)(ws + WS_LOSS);

    k0_see<<<4, 256, 0, stream>>>(emb, see, loss);
    k_sxx<<<512, 64, 0, stream>>>(x, sxx, key);
    k1_dist<<<1024, 256, 0, stream>>>(x, emb, see, sxx, key);
    k3_out<<<1024, 256, 0, stream>>>(x, emb, key, dout, loss);
    k4_fin<<<1, 1, 0, stream>>>(loss, dout);
}

// Round 6
// 348.274 us; speedup vs baseline: 1.0928x; 1.0928x over previous
//
#include <hip/hip_runtime.h>

#define LOSS_OFF 8388608
#define IDX_OFF  8388609

// ws layout (bytes)
#define WS_SEE   0          // float[1024]
#define WS_SXX   4096       // float[32768]            -> 135168
#define WS_KEY   135168     // u64[32768]              -> 397312
#define WS_LOSS  397312     // double
#define WS_EPAD  397440     // padded E^T [2][256][640] words = 1310720 B -> ends ~1.71 MB

#define FLT_BIG  3.402823466e+38f

// async global->LDS, 16B per lane; LDS dest = wave-uniform base + lane*16
#define GLD16(gp, lp) __builtin_amdgcn_global_load_lds( \
    (const __attribute__((address_space(1))) unsigned int*)(gp), \
    (__attribute__((address_space(3))) unsigned int*)(lp), 16, 0, 0)

// numpy pairwise_sum of 256 squared elements, bit-exact (see round-2 notes).
__device__ __forceinline__ float np_sumsq256(const float* __restrict__ p, int stride) {
    float s[2];
#pragma unroll
    for (int half = 0; half < 2; half++) {
        const float* a = p + half * 128 * stride;
        float r[8];
#pragma unroll
        for (int l = 0; l < 8; l++) {
            float v = a[l * stride];
            float sq = v * v;
            asm volatile("" : "+v"(sq));   // forbid fma contraction into the add chain
            r[l] = sq;
        }
#pragma unroll
        for (int i = 8; i < 128; i += 8) {
#pragma unroll
            for (int l = 0; l < 8; l++) {
                float v = a[(i + l) * stride];
                float sq = v * v;
                asm volatile("" : "+v"(sq));
                r[l] = r[l] + sq;
            }
        }
        s[half] = ((r[0] + r[1]) + (r[2] + r[3])) + ((r[4] + r[5]) + (r[6] + r[7]));
    }
    return s[0] + s[1];
}

__device__ __forceinline__ unsigned int f32_sortable(float m) {
    unsigned int u = __float_as_uint(m);
    return u ^ (((unsigned int)((int)u >> 31)) | 0x80000000u);
}

// ---------------- k0: codebook ||e||^2 (np semantics) + init ----------------
__global__ __launch_bounds__(256) void k0_see(const float* __restrict__ emb,
                                              float* __restrict__ see,
                                              double* __restrict__ loss) {
    const int k = blockIdx.x * 256 + threadIdx.x;   // grid 4 x 256
    see[k] = np_sumsq256(emb + (size_t)k * 256, 1);
    if (k == 0) { *loss = 0.0; }
}

// ---------------- k_epad: build padded half-major E^T ----------------
// epad[half][c][g*20 + w] = emb[half*512 + g*16 + w][c]   (word indices)
// 80 B group stride => k1's 8-distinct-address b128 reads are bank-conflict-free,
// and each (half, c-chunk) is a CONTIGUOUS 40 KB global range for global_load_lds.
__global__ __launch_bounds__(256) void k_epad(const float* __restrict__ emb,
                                              float* __restrict__ epad) {
    __shared__ float T[256][17];
    const int t  = threadIdx.x;
    const int k0 = blockIdx.x << 4;            // 16 codes per block, grid 64
    const int kr = t >> 4, cs = (t & 15) << 4;
#pragma unroll
    for (int j = 0; j < 4; j++) {
        const float4 v = *(const float4*)(emb + (size_t)(k0 + kr) * 256 + cs + j * 4);
        T[cs + j * 4 + 0][kr] = v.x;
        T[cs + j * 4 + 1][kr] = v.y;
        T[cs + j * 4 + 2][kr] = v.z;
        T[cs + j * 4 + 3][kr] = v.w;
    }
    __syncthreads();
    const int half = k0 >> 9;
    const int g    = (k0 & 511) >> 4;
    float* dst = epad + (size_t)half * 163840 + (size_t)t * 640 + g * 20;
#pragma unroll
    for (int j = 0; j < 4; j++) {
        float4 v;
        v.x = T[t][j * 4 + 0]; v.y = T[t][j * 4 + 1];
        v.z = T[t][j * 4 + 2]; v.w = T[t][j * 4 + 3];
        *(float4*)(dst + j * 4) = v;
    }
}

// ---------------- k_sxx: per-row ||x||^2 (np semantics) + key init ----------------
__global__ __launch_bounds__(64) void k_sxx(const float* __restrict__ x,
                                            float* __restrict__ sxx,
                                            unsigned long long* __restrict__ key) {
    const int n = blockIdx.x * 64 + threadIdx.x;    // grid 512 x 64
    const int b = n >> 10, hw = n & 1023;
    sxx[n] = np_sumsq256(x + (size_t)b * 262144 + hw, 1024);
    key[n] = ~0ull;
}

// ---------------- k1: fp32 GEMM distances + np-rounded argmin ----------------
// grid 1024 (= 512 row-blocks x 2 K-halves), block 256 threads (4 waves).
// Block tile 64 rows x 512 codes; thread tile 8 rows x 16 codes (0.75 B/FMA).
// Staging: pure global_load_lds width-16 (X linear; E via padded-contiguous EPAD).
// LDS 46 KB, __launch_bounds__(256,2) -> 2 blocks/CU for barrier overlap.
// dot = sequential fp32 FMA chain over c=0..255 (bit-matches np reference).
__global__ __launch_bounds__(256, 2) void k1_dist(const float* __restrict__ x,
                                                  const float* __restrict__ epad,
                                                  const float* __restrict__ see_g,
                                                  const float* __restrict__ sxx_g,
                                                  unsigned long long* __restrict__ key) {
    __shared__ float smem[11776];
    float* Xs   = smem;             // [16 c][64 r]           words 0..1023
    float* Es   = smem + 1024;      // [16 c][640 w] padded   words 1024..11263
    float* sees = smem + 11264;     // [512]

    const int t    = threadIdx.x;
    const int blk  = blockIdx.x;
    const int rb   = blk >> 1;      // row block 0..511 (64 rows)
    const int half = blk & 1;       // code half
    const int b    = rb >> 4;
    const int rem0 = (rb & 15) << 6;

    const char* xb  = (const char*)(x + (size_t)b * 262144 + rem0);
    const char* epb = (const char*)epad + (size_t)half * 655360;

    const int tr = t & 7;           // rows 8*tr .. 8*tr+7
    const int tk = t >> 3;          // code group: codes half*512 + 16*tk .. +15
    const int w  = t >> 6;          // wave id (uniform per wave)
    const int l  = t & 63;          // lane

    sees[t]       = see_g[half * 512 + t];
    sees[t + 256] = see_g[half * 512 + 256 + t];

    float sx[8];
#pragma unroll
    for (int i = 0; i < 8; i++) sx[i] = sxx_g[rb * 64 + 8 * tr + i];

    float acc[8][16];
#pragma unroll
    for (int i = 0; i < 8; i++)
#pragma unroll
        for (int j = 0; j < 16; j++) acc[i][j] = 0.f;

    // wave-uniform LDS byte bases
    char* xs_base = (char*)smem + w * 1024;                 // Xs: 4 KB total
    char* es_base = (char*)smem + 4096 + w * 10240;         // Es: 40 KB total

    for (int cc = 0; cc < 16; cc++) {
        const int cb = cc * 16;
        __syncthreads();                    // prior chunk's LDS reads done
        // stage X chunk [16 c][64 r] = 4 KB: 1 instr/thread, linear LDS image
        GLD16(xb + (size_t)(cb + w * 4 + (l >> 4)) * 4096 + (size_t)(l & 15) * 16,
              xs_base);
        // stage E chunk = contiguous 40 KB of EPAD: 10 instrs/thread
        {
            const char* eg = epb + (size_t)cb * 2560 + (size_t)w * 10240 + (size_t)l * 16;
#pragma unroll
            for (int i = 0; i < 10; i++)
                GLD16(eg + i * 1024, es_base + i * 1024);
        }
        __syncthreads();                    // drains vmcnt -> LDS populated
        // sequential fp32 FMA chain over c (bit-matches np sequential dot)
#pragma unroll 4
        for (int c = 0; c < 16; c++) {
            float a[8], bv[16];
            *(float4*)&a[0]   = *(const float4*)(Xs + c * 64 + 8 * tr);
            *(float4*)&a[4]   = *(const float4*)(Xs + c * 64 + 8 * tr + 4);
            const float* eb   = Es + c * 640 + tk * 20;
            *(float4*)&bv[0]  = *(const float4*)(eb);
            *(float4*)&bv[4]  = *(const float4*)(eb + 4);
            *(float4*)&bv[8]  = *(const float4*)(eb + 8);
            *(float4*)&bv[12] = *(const float4*)(eb + 12);
#pragma unroll
            for (int i = 0; i < 8; i++)
#pragma unroll
                for (int j = 0; j < 16; j++)
                    acc[i][j] = fmaf(a[i], bv[j], acc[i][j]);
        }
    }

    // fold: q = fl(fl(sxx - 2*dot) + see); jj ascending = k ascending (first-min)
    float bm1[8]; int bi1[8];
#pragma unroll
    for (int i = 0; i < 8; i++) { bm1[i] = FLT_BIG; bi1[i] = 0; }
#pragma unroll
    for (int i = 0; i < 8; i++) {
#pragma unroll
        for (int jj = 0; jj < 16; jj++) {
            const int kloc = tk * 16 + jj;
            const float t1 = fmaf(-2.f, acc[i][jj], sx[i]);
            const float qd = t1 + sees[kloc];
            if (qd < bm1[i]) { bm1[i] = qd; bi1[i] = half * 512 + kloc; }
        }
    }

    // cross-thread reduction (32 tk-groups, ascending g = ascending k)
    __syncthreads();
    float* rm1 = smem;                 // [64][33] floats
    int*   ri1 = (int*)(smem + 2112);  // [64][33] ints
#pragma unroll
    for (int i = 0; i < 8; i++) {
        const int r = 8 * tr + i;
        rm1[r * 33 + tk] = bm1[i];
        ri1[r * 33 + tk] = bi1[i];
    }
    __syncthreads();
    if (t < 64) {
        const int r = t;
        float M1 = FLT_BIG; int I1 = 0x7fffffff;
        for (int g = 0; g < 32; g++) {
            const float m1 = rm1[r * 33 + g];
            const int   i1 = ri1[r * 33 + g];
            if (m1 < M1)       { M1 = m1; I1 = i1; }
            else if (m1 == M1) { I1 = min(I1, i1); }
        }
        const unsigned long long pk =
            ((unsigned long long)f32_sortable(M1) << 32) | (unsigned int)I1;
        atomicMin(&key[rb * 64 + r], pk);
    }
}

// ---------------- k3: gather quantized + loss partials + indices ----------------
__global__ __launch_bounds__(256) void k3_out(const float* __restrict__ x,
                                              const float* __restrict__ emb,
                                              const unsigned long long* __restrict__ key,
                                              float* __restrict__ dout,
                                              double* __restrict__ loss) {
    __shared__ float elds[32][257];
    __shared__ int   idxs[32];
    __shared__ float red[256];
    const int t  = threadIdx.x;
    const int bh = blockIdx.x;
    const int b = bh >> 5, h = bh & 31;
    if (t < 32) idxs[t] = (int)(key[(bh << 5) + t] & 0xffffffffull);
    __syncthreads();
    for (int r = 0; r < 32; r++) elds[r][t] = emb[(size_t)idxs[r] * 256 + t];
    __syncthreads();
    const int w = t & 31, cg = t >> 5;
    const size_t base = (size_t)b * 262144 + (size_t)(h * 32 + w);
    float acc = 0.f;
#pragma unroll 4
    for (int s = 0; s < 32; s++) {
        const int c = (cg << 5) + s;
        const float q  = elds[w][c];
        const float xv = x[base + (size_t)c * 1024];
        dout[base + (size_t)c * 1024] = q;
        const float d = q - xv;
        acc = fmaf(d, d, acc);
    }
    red[t] = acc;
    __syncthreads();
    for (int s = 128; s > 0; s >>= 1) {
        if (t < s) red[t] += red[t + s];
        __syncthreads();
    }
    if (t == 0) atomicAdd(loss, (double)red[0]);
    if (t < 32) dout[IDX_OFF + (bh << 5) + t] = (float)idxs[t];
}

// ---------------- k4: finalize loss ----------------
__global__ void k4_fin(const double* __restrict__ loss, float* __restrict__ dout) {
    dout[LOSS_OFF] = (float)(1.25 * (*loss) / 8388608.0);
}

extern "C" void kernel_launch(void* const* d_in, const int* in_sizes, int n_in,
                              void* d_out, int out_size, void* d_ws, size_t ws_size,
                              hipStream_t stream) {
    const float* x   = (const float*)d_in[0];
    const float* emb = (const float*)d_in[1];
    float* dout = (float*)d_out;
    char* ws = (char*)d_ws;
    float*  see  = (float*)(ws + WS_SEE);
    float*  sxx  = (float*)(ws + WS_SXX);
    unsigned long long* key = (unsigned long long*)(ws + WS_KEY);
    double* loss = (double*)(ws + WS_LOSS);
    float*  epad = (float*)(ws + WS_EPAD);

    k0_see<<<4, 256, 0, stream>>>(emb, see, loss);
    k_epad<<<64, 256, 0, stream>>>(emb, epad);
    k_sxx<<<512, 64, 0, stream>>>(x, sxx, key);
    k1_dist<<<1024, 256, 0, stream>>>(x, epad, see, sxx, key);
    k3_out<<<1024, 256, 0, stream>>>(x, emb, key, dout, loss);
    k4_fin<<<1, 1, 0, stream>>>(loss, dout);
}

// Round 7
// 324.560 us; speedup vs baseline: 1.1727x; 1.0731x over previous
//
#include <hip/hip_runtime.h>

#define LOSS_OFF 8388608
#define IDX_OFF  8388609

// ws layout (bytes)
#define WS_SEE   0          // float[1024]
#define WS_SXX   4096       // float[32768]            -> 135168
#define WS_KEY   135168     // u64[32768]              -> 397312
#define WS_LOSS  397312     // double
#define WS_EPAD  397440     // padded E^T [2][256][640] words = 1310720 B -> ends ~1.71 MB

#define FLT_BIG  3.402823466e+38f

// async global->LDS, 16B per lane; LDS dest = wave-uniform base + lane*16
#define GLD16(gp, lp) __builtin_amdgcn_global_load_lds( \
    (const __attribute__((address_space(1))) unsigned int*)(gp), \
    (__attribute__((address_space(3))) unsigned int*)(lp), 16, 0, 0)

// numpy pairwise_sum of 256 squared elements, bit-exact (see round-2 notes).
__device__ __forceinline__ float np_sumsq256(const float* __restrict__ p, int stride) {
    float s[2];
#pragma unroll
    for (int half = 0; half < 2; half++) {
        const float* a = p + half * 128 * stride;
        float r[8];
#pragma unroll
        for (int l = 0; l < 8; l++) {
            float v = a[l * stride];
            float sq = v * v;
            asm volatile("" : "+v"(sq));   // forbid fma contraction into the add chain
            r[l] = sq;
        }
#pragma unroll
        for (int i = 8; i < 128; i += 8) {
#pragma unroll
            for (int l = 0; l < 8; l++) {
                float v = a[(i + l) * stride];
                float sq = v * v;
                asm volatile("" : "+v"(sq));
                r[l] = r[l] + sq;
            }
        }
        s[half] = ((r[0] + r[1]) + (r[2] + r[3])) + ((r[4] + r[5]) + (r[6] + r[7]));
    }
    return s[0] + s[1];
}

__device__ __forceinline__ unsigned int f32_sortable(float m) {
    unsigned int u = __float_as_uint(m);
    return u ^ (((unsigned int)((int)u >> 31)) | 0x80000000u);
}

// ---------------- k0: codebook ||e||^2 (np semantics) + init ----------------
__global__ __launch_bounds__(256) void k0_see(const float* __restrict__ emb,
                                              float* __restrict__ see,
                                              double* __restrict__ loss) {
    const int k = blockIdx.x * 256 + threadIdx.x;   // grid 4 x 256
    see[k] = np_sumsq256(emb + (size_t)k * 256, 1);
    if (k == 0) { *loss = 0.0; }
}

// ---------------- k_epad: build padded half-major E^T ----------------
// epad[half][c][g*20 + w] = emb[half*512 + g*16 + w][c]   (word indices)
__global__ __launch_bounds__(256) void k_epad(const float* __restrict__ emb,
                                              float* __restrict__ epad) {
    __shared__ float T[256][17];
    const int t  = threadIdx.x;
    const int k0 = blockIdx.x << 4;            // 16 codes per block, grid 64
    const int kr = t >> 4, cs = (t & 15) << 4;
#pragma unroll
    for (int j = 0; j < 4; j++) {
        const float4 v = *(const float4*)(emb + (size_t)(k0 + kr) * 256 + cs + j * 4);
        T[cs + j * 4 + 0][kr] = v.x;
        T[cs + j * 4 + 1][kr] = v.y;
        T[cs + j * 4 + 2][kr] = v.z;
        T[cs + j * 4 + 3][kr] = v.w;
    }
    __syncthreads();
    const int half = k0 >> 9;
    const int g    = (k0 & 511) >> 4;
    float* dst = epad + (size_t)half * 163840 + (size_t)t * 640 + g * 20;
#pragma unroll
    for (int j = 0; j < 4; j++) {
        float4 v;
        v.x = T[t][j * 4 + 0]; v.y = T[t][j * 4 + 1];
        v.z = T[t][j * 4 + 2]; v.w = T[t][j * 4 + 3];
        *(float4*)(dst + j * 4) = v;
    }
}

// ---------------- k_sxx: per-row ||x||^2 (np semantics) + key init ----------------
__global__ __launch_bounds__(64) void k_sxx(const float* __restrict__ x,
                                            float* __restrict__ sxx,
                                            unsigned long long* __restrict__ key) {
    const int n = blockIdx.x * 64 + threadIdx.x;    // grid 512 x 64
    const int b = n >> 10, hw = n & 1023;
    sxx[n] = np_sumsq256(x + (size_t)b * 262144 + hw, 1024);
    key[n] = ~0ull;
}

// ---------------- k1: fp32 GEMM distances + np-rounded argmin ----------------
// grid 1024 (= 512 row-blocks x 2 K-halves), block 256 threads (4 waves).
// Block tile 64 rows x 512 codes; thread tile 8 rows x 16 codes (0.75 B/FMA).
// Staging: pure global_load_lds width-16 (X linear; E via padded-contiguous EPAD).
// amdgpu_waves_per_eu(2,2): pin VGPR budget to 256/wave so acc[8][16]=128 regs
// stays in arch VGPRs (round-6 let the allocator target 4 waves/EU at 120 VGPR
// and churn the accumulator through AGPR copies -> +80% VALU issue).
__global__ __launch_bounds__(256)
__attribute__((amdgpu_waves_per_eu(2, 2)))
void k1_dist(const float* __restrict__ x,
             const float* __restrict__ epad,
             const float* __restrict__ see_g,
             const float* __restrict__ sxx_g,
             unsigned long long* __restrict__ key) {
    __shared__ float smem[11776];
    float* Xs   = smem;             // [16 c][64 r]           words 0..1023
    float* Es   = smem + 1024;      // [16 c][640 w] padded   words 1024..11263
    float* sees = smem + 11264;     // [512]

    const int t    = threadIdx.x;
    const int blk  = blockIdx.x;
    const int rb   = blk >> 1;      // row block 0..511 (64 rows)
    const int half = blk & 1;       // code half
    const int b    = rb >> 4;
    const int rem0 = (rb & 15) << 6;

    const char* xb  = (const char*)(x + (size_t)b * 262144 + rem0);
    const char* epb = (const char*)epad + (size_t)half * 655360;

    const int tr = t & 7;           // rows 8*tr .. 8*tr+7
    const int tk = t >> 3;          // code group: codes half*512 + 16*tk .. +15
    const int w  = t >> 6;          // wave id (uniform per wave)
    const int l  = t & 63;          // lane

    sees[t]       = see_g[half * 512 + t];
    sees[t + 256] = see_g[half * 512 + 256 + t];

    float acc[8][16];
#pragma unroll
    for (int i = 0; i < 8; i++)
#pragma unroll
        for (int j = 0; j < 16; j++) acc[i][j] = 0.f;

    // wave-uniform LDS byte bases
    char* xs_base = (char*)smem + w * 1024;                 // Xs: 4 KB total
    char* es_base = (char*)smem + 4096 + w * 10240;         // Es: 40 KB total

    for (int cc = 0; cc < 16; cc++) {
        const int cb = cc * 16;
        __syncthreads();                    // prior chunk's LDS reads done
        // stage X chunk [16 c][64 r] = 4 KB: 1 instr/thread, linear LDS image
        GLD16(xb + (size_t)(cb + w * 4 + (l >> 4)) * 4096 + (size_t)(l & 15) * 16,
              xs_base);
        // stage E chunk = contiguous 40 KB of EPAD: 10 instrs/thread
        {
            const char* eg = epb + (size_t)cb * 2560 + (size_t)w * 10240 + (size_t)l * 16;
#pragma unroll
            for (int i = 0; i < 10; i++)
                GLD16(eg + i * 1024, es_base + i * 1024);
        }
        __syncthreads();                    // drains vmcnt -> LDS populated
        // sequential fp32 FMA chain over c (bit-matches np sequential dot);
        // bv consumed in float4 chunks to keep live operand set small
#pragma unroll 2
        for (int c = 0; c < 16; c++) {
            float a[8];
            *(float4*)&a[0] = *(const float4*)(Xs + c * 64 + 8 * tr);
            *(float4*)&a[4] = *(const float4*)(Xs + c * 64 + 8 * tr + 4);
            const float* eb = Es + c * 640 + tk * 20;
#pragma unroll
            for (int jq = 0; jq < 4; jq++) {
                float bv[4];
                *(float4*)&bv[0] = *(const float4*)(eb + jq * 4);
#pragma unroll
                for (int i = 0; i < 8; i++)
#pragma unroll
                    for (int j = 0; j < 4; j++)
                        acc[i][jq * 4 + j] = fmaf(a[i], bv[j], acc[i][jq * 4 + j]);
            }
        }
    }

    // sx loaded AFTER the K-loop (keeps 8 regs out of the hot live range)
    float sx[8];
#pragma unroll
    for (int i = 0; i < 8; i++) sx[i] = sxx_g[rb * 64 + 8 * tr + i];

    // fold: q = fl(fl(sxx - 2*dot) + see); jj ascending = k ascending (first-min)
    float bm1[8]; int bi1[8];
#pragma unroll
    for (int i = 0; i < 8; i++) { bm1[i] = FLT_BIG; bi1[i] = 0; }
#pragma unroll
    for (int i = 0; i < 8; i++) {
#pragma unroll
        for (int jj = 0; jj < 16; jj++) {
            const int kloc = tk * 16 + jj;
            const float t1 = fmaf(-2.f, acc[i][jj], sx[i]);
            const float qd = t1 + sees[kloc];
            if (qd < bm1[i]) { bm1[i] = qd; bi1[i] = half * 512 + kloc; }
        }
    }

    // cross-thread reduction (32 tk-groups, ascending g = ascending k)
    __syncthreads();
    float* rm1 = smem;                 // [64][33] floats
    int*   ri1 = (int*)(smem + 2112);  // [64][33] ints
#pragma unroll
    for (int i = 0; i < 8; i++) {
        const int r = 8 * tr + i;
        rm1[r * 33 + tk] = bm1[i];
        ri1[r * 33 + tk] = bi1[i];
    }
    __syncthreads();
    if (t < 64) {
        const int r = t;
        float M1 = FLT_BIG; int I1 = 0x7fffffff;
        for (int g = 0; g < 32; g++) {
            const float m1 = rm1[r * 33 + g];
            const int   i1 = ri1[r * 33 + g];
            if (m1 < M1)       { M1 = m1; I1 = i1; }
            else if (m1 == M1) { I1 = min(I1, i1); }
        }
        const unsigned long long pk =
            ((unsigned long long)f32_sortable(M1) << 32) | (unsigned int)I1;
        atomicMin(&key[rb * 64 + r], pk);
    }
}

// ---------------- k3: gather quantized + loss partials + indices ----------------
__global__ __launch_bounds__(256) void k3_out(const float* __restrict__ x,
                                              const float* __restrict__ emb,
                                              const unsigned long long* __restrict__ key,
                                              float* __restrict__ dout,
                                              double* __restrict__ loss) {
    __shared__ float elds[32][257];
    __shared__ int   idxs[32];
    __shared__ float red[256];
    const int t  = threadIdx.x;
    const int bh = blockIdx.x;
    const int b = bh >> 5, h = bh & 31;
    if (t < 32) idxs[t] = (int)(key[(bh << 5) + t] & 0xffffffffull);
    __syncthreads();
    for (int r = 0; r < 32; r++) elds[r][t] = emb[(size_t)idxs[r] * 256 + t];
    __syncthreads();
    const int w = t & 31, cg = t >> 5;
    const size_t base = (size_t)b * 262144 + (size_t)(h * 32 + w);
    float acc = 0.f;
#pragma unroll 4
    for (int s = 0; s < 32; s++) {
        const int c = (cg << 5) + s;
        const float q  = elds[w][c];
        const float xv = x[base + (size_t)c * 1024];
        dout[base + (size_t)c * 1024] = q;
        const float d = q - xv;
        acc = fmaf(d, d, acc);
    }
    red[t] = acc;
    __syncthreads();
    for (int s = 128; s > 0; s >>= 1) {
        if (t < s) red[t] += red[t + s];
        __syncthreads();
    }
    if (t == 0) atomicAdd(loss, (double)red[0]);
    if (t < 32) dout[IDX_OFF + (bh << 5) + t] = (float)idxs[t];
}

// ---------------- k4: finalize loss ----------------
__global__ void k4_fin(const double* __restrict__ loss, float* __restrict__ dout) {
    dout[LOSS_OFF] = (float)(1.25 * (*loss) / 8388608.0);
}

extern "C" void kernel_launch(void* const* d_in, const int* in_sizes, int n_in,
                              void* d_out, int out_size, void* d_ws, size_t ws_size,
                              hipStream_t stream) {
    const float* x   = (const float*)d_in[0];
    const float* emb = (const float*)d_in[1];
    float* dout = (float*)d_out;
    char* ws = (char*)d_ws;
    float*  see  = (float*)(ws + WS_SEE);
    float*  sxx  = (float*)(ws + WS_SXX);
    unsigned long long* key = (unsigned long long*)(ws + WS_KEY);
    double* loss = (double*)(ws + WS_LOSS);
    float*  epad = (float*)(ws + WS_EPAD);

    k0_see<<<4, 256, 0, stream>>>(emb, see, loss);
    k_epad<<<64, 256, 0, stream>>>(emb, epad);
    k_sxx<<<512, 64, 0, stream>>>(x, sxx, key);
    k1_dist<<<1024, 256, 0, stream>>>(x, epad, see, sxx, key);
    k3_out<<<1024, 256, 0, stream>>>(x, emb, key, dout, loss);
    k4_fin<<<1, 1, 0, stream>>>(loss, dout);
}

// Round 8
// 316.342 us; speedup vs baseline: 1.2031x; 1.0260x over previous
//
#include <hip/hip_runtime.h>

#define LOSS_OFF 8388608
#define IDX_OFF  8388609

// ws layout (bytes)
#define WS_SEE   0          // float[1024]
#define WS_SXX   4096       // float[32768]            -> 135168
#define WS_KEY   135168     // u64[32768]              -> 397312
#define WS_LOSS  397312     // double
#define WS_ET    397440     // eT[c][k] float[256][1024] = 1 MB (64B-aligned)

#define FLT_BIG  3.402823466e+38f

// numpy pairwise_sum of 256 squared elements, bit-exact (see round-2 notes).
__device__ __forceinline__ float np_sumsq256(const float* __restrict__ p, int stride) {
    float s[2];
#pragma unroll
    for (int half = 0; half < 2; half++) {
        const float* a = p + half * 128 * stride;
        float r[8];
#pragma unroll
        for (int l = 0; l < 8; l++) {
            float v = a[l * stride];
            float sq = v * v;
            asm volatile("" : "+v"(sq));   // forbid fma contraction into the add chain
            r[l] = sq;
        }
#pragma unroll
        for (int i = 8; i < 128; i += 8) {
#pragma unroll
            for (int l = 0; l < 8; l++) {
                float v = a[(i + l) * stride];
                float sq = v * v;
                asm volatile("" : "+v"(sq));
                r[l] = r[l] + sq;
            }
        }
        s[half] = ((r[0] + r[1]) + (r[2] + r[3])) + ((r[4] + r[5]) + (r[6] + r[7]));
    }
    return s[0] + s[1];
}

__device__ __forceinline__ unsigned int f32_sortable(float m) {
    unsigned int u = __float_as_uint(m);
    return u ^ (((unsigned int)((int)u >> 31)) | 0x80000000u);
}

// ---------------- k0: codebook ||e||^2 (np semantics) + init ----------------
__global__ __launch_bounds__(256) void k0_see(const float* __restrict__ emb,
                                              float* __restrict__ see,
                                              double* __restrict__ loss) {
    const int k = blockIdx.x * 256 + threadIdx.x;   // grid 4 x 256
    see[k] = np_sumsq256(emb + (size_t)k * 256, 1);
    if (k == 0) { *loss = 0.0; }
}

// ---------------- k_et: transpose codebook -> eT[c][k] ----------------
// grid 64 x 256: block handles 16 codes x all 256 c.
__global__ __launch_bounds__(256) void k_et(const float* __restrict__ emb,
                                            float* __restrict__ eT) {
    __shared__ float T[256][17];
    const int t  = threadIdx.x;
    const int k0 = blockIdx.x << 4;
    const int kr = t >> 4, cs = (t & 15) << 4;
#pragma unroll
    for (int j = 0; j < 4; j++) {
        const float4 v = *(const float4*)(emb + (size_t)(k0 + kr) * 256 + cs + j * 4);
        T[cs + j * 4 + 0][kr] = v.x;
        T[cs + j * 4 + 1][kr] = v.y;
        T[cs + j * 4 + 2][kr] = v.z;
        T[cs + j * 4 + 3][kr] = v.w;
    }
    __syncthreads();
    float* dst = eT + (size_t)t * 1024 + k0;   // row c = t, 16 consecutive codes
#pragma unroll
    for (int j = 0; j < 4; j++) {
        float4 v;
        v.x = T[t][j * 4 + 0]; v.y = T[t][j * 4 + 1];
        v.z = T[t][j * 4 + 2]; v.w = T[t][j * 4 + 3];
        *(float4*)(dst + j * 4) = v;
    }
}

// ---------------- k_sxx: per-row ||x||^2 (np semantics) + key init ----------------
__global__ __launch_bounds__(64) void k_sxx(const float* __restrict__ x,
                                            float* __restrict__ sxx,
                                            unsigned long long* __restrict__ key) {
    const int n = blockIdx.x * 64 + threadIdx.x;    // grid 512 x 64
    const int b = n >> 10, hw = n & 1023;
    sxx[n] = np_sumsq256(x + (size_t)b * 262144 + hw, 1024);
    key[n] = ~0ull;
}

// ---------------- k1: SGPR-B distance + argmin ----------------
// grid 8192 (= 512 row-sets x 16 code-blocks), block 256 threads (4 waves).
// Wave: 64 rows (one per lane) x 16 codes (wave-uniform -> SGPR bv).
// Per c-step: 1 coalesced global_load_dword (a), 1 uniform 64B load (bv),
// 16 v_fma_f32 (SGPR operand). No LDS/barriers in hot loop; acc = 16 VGPR.
// dot = sequential fp32 FMA chain over c=0..255 (bit-matches np reference).
__global__ __launch_bounds__(256) void k1_dist(const float* __restrict__ x,
                                               const float* __restrict__ eT,
                                               const float* __restrict__ see_g,
                                               const float* __restrict__ sxx_g,
                                               unsigned long long* __restrict__ key) {
    const int t  = threadIdx.x;
    const int l  = t & 63;
    const int wv = __builtin_amdgcn_readfirstlane(t >> 6);   // 0..3, uniform
    const int bid = blockIdx.x;
    const int rs  = bid >> 4;                 // row-set (64 rows)
    const int q   = bid & 15;                 // code-block (64 codes)
    const int k0  = q * 64 + wv * 16;         // wave's codes (uniform)
    const int b   = rs >> 4;
    const int hw0 = (rs & 15) << 6;
    const int n   = rs * 64 + l;

    const float* __restrict__ xc = x  + (size_t)b * 262144 + hw0 + l;  // +1024/c
    const float* __restrict__ ec = eT + k0;                            // +1024/c

    float acc[16];
#pragma unroll
    for (int j = 0; j < 16; j++) acc[j] = 0.f;

    // software pipeline: (a, bv) for steps c and c+1 preloaded
    float a0 = xc[0];
    float a1 = xc[1024];
    float b0[16], b1[16];
#pragma unroll
    for (int j = 0; j < 16; j++) b0[j] = ec[j];
#pragma unroll
    for (int j = 0; j < 16; j++) b1[j] = ec[1024 + j];

#pragma unroll 2
    for (int c = 0; c < 252; c += 2) {
        const float a2 = xc[(size_t)(c + 2) * 1024];
        const float a3 = xc[(size_t)(c + 3) * 1024];
        float b2[16], b3[16];
#pragma unroll
        for (int j = 0; j < 16; j++) b2[j] = ec[(size_t)(c + 2) * 1024 + j];
#pragma unroll
        for (int j = 0; j < 16; j++) b3[j] = ec[(size_t)(c + 3) * 1024 + j];
#pragma unroll
        for (int j = 0; j < 16; j++) acc[j] = fmaf(a0, b0[j], acc[j]);
#pragma unroll
        for (int j = 0; j < 16; j++) acc[j] = fmaf(a1, b1[j], acc[j]);
        a0 = a2; a1 = a3;
#pragma unroll
        for (int j = 0; j < 16; j++) { b0[j] = b2[j]; b1[j] = b3[j]; }
    }
    // c = 252, 253 (in pipeline regs)
#pragma unroll
    for (int j = 0; j < 16; j++) acc[j] = fmaf(a0, b0[j], acc[j]);
#pragma unroll
    for (int j = 0; j < 16; j++) acc[j] = fmaf(a1, b1[j], acc[j]);
    // c = 254, 255
    {
        const float a4 = xc[(size_t)254 * 1024];
        const float a5 = xc[(size_t)255 * 1024];
        float b4[16], b5[16];
#pragma unroll
        for (int j = 0; j < 16; j++) b4[j] = ec[(size_t)254 * 1024 + j];
#pragma unroll
        for (int j = 0; j < 16; j++) b5[j] = ec[(size_t)255 * 1024 + j];
#pragma unroll
        for (int j = 0; j < 16; j++) acc[j] = fmaf(a4, b4[j], acc[j]);
#pragma unroll
        for (int j = 0; j < 16; j++) acc[j] = fmaf(a5, b5[j], acc[j]);
    }

    // fold: q = fl(fl(sxx - 2*dot) + see); packed (sortable(q),k) min ==
    // min distance then lowest index == numpy first-occurrence argmin.
    const float sx = sxx_g[n];
    unsigned long long best = ~0ull;
#pragma unroll
    for (int j = 0; j < 16; j++) {
        const float t1 = fmaf(-2.f, acc[j], sx);
        const float qd = t1 + see_g[k0 + j];
        const unsigned long long pk =
            ((unsigned long long)f32_sortable(qd) << 32) | (unsigned int)(k0 + j);
        best = pk < best ? pk : best;
    }

    // in-block reduce (4 waves) then one atomicMin per row per block
    __shared__ unsigned long long red[4][64];
    red[wv][l] = best;
    __syncthreads();
    if (t < 64) {
        unsigned long long m = red[0][t];
        m = red[1][t] < m ? red[1][t] : m;
        m = red[2][t] < m ? red[2][t] : m;
        m = red[3][t] < m ? red[3][t] : m;
        atomicMin(&key[rs * 64 + t], m);
    }
}

// ---------------- k3: gather quantized + loss partials + indices ----------------
__global__ __launch_bounds__(256) void k3_out(const float* __restrict__ x,
                                              const float* __restrict__ emb,
                                              const unsigned long long* __restrict__ key,
                                              float* __restrict__ dout,
                                              double* __restrict__ loss) {
    __shared__ float elds[32][257];
    __shared__ int   idxs[32];
    __shared__ float red[256];
    const int t  = threadIdx.x;
    const int bh = blockIdx.x;
    const int b = bh >> 5, h = bh & 31;
    if (t < 32) idxs[t] = (int)(key[(bh << 5) + t] & 0xffffffffull);
    __syncthreads();
    for (int r = 0; r < 32; r++) elds[r][t] = emb[(size_t)idxs[r] * 256 + t];
    __syncthreads();
    const int w = t & 31, cg = t >> 5;
    const size_t base = (size_t)b * 262144 + (size_t)(h * 32 + w);
    float acc = 0.f;
#pragma unroll 4
    for (int s = 0; s < 32; s++) {
        const int c = (cg << 5) + s;
        const float q  = elds[w][c];
        const float xv = x[base + (size_t)c * 1024];
        dout[base + (size_t)c * 1024] = q;
        const float d = q - xv;
        acc = fmaf(d, d, acc);
    }
    red[t] = acc;
    __syncthreads();
    for (int s = 128; s > 0; s >>= 1) {
        if (t < s) red[t] += red[t + s];
        __syncthreads();
    }
    if (t == 0) atomicAdd(loss, (double)red[0]);
    if (t < 32) dout[IDX_OFF + (bh << 5) + t] = (float)idxs[t];
}

// ---------------- k4: finalize loss ----------------
__global__ void k4_fin(const double* __restrict__ loss, float* __restrict__ dout) {
    dout[LOSS_OFF] = (float)(1.25 * (*loss) / 8388608.0);
}

extern "C" void kernel_launch(void* const* d_in, const int* in_sizes, int n_in,
                              void* d_out, int out_size, void* d_ws, size_t ws_size,
                              hipStream_t stream) {
    const float* x   = (const float*)d_in[0];
    const float* emb = (const float*)d_in[1];
    float* dout = (float*)d_out;
    char* ws = (char*)d_ws;
    float*  see  = (float*)(ws + WS_SEE);
    float*  sxx  = (float*)(ws + WS_SXX);
    unsigned long long* key = (unsigned long long*)(ws + WS_KEY);
    double* loss = (double*)(ws + WS_LOSS);
    float*  eT   = (float*)(ws + WS_ET);

    k0_see<<<4, 256, 0, stream>>>(emb, see, loss);
    k_et<<<64, 256, 0, stream>>>(emb, eT);
    k_sxx<<<512, 64, 0, stream>>>(x, sxx, key);
    k1_dist<<<8192, 256, 0, stream>>>(x, eT, see, sxx, key);
    k3_out<<<1024, 256, 0, stream>>>(x, emb, key, dout, loss);
    k4_fin<<<1, 1, 0, stream>>>(loss, dout);
}

// Round 9
// 306.191 us; speedup vs baseline: 1.2430x; 1.0332x over previous
//
#include <hip/hip_runtime.h>

#define LOSS_OFF 8388608
#define IDX_OFF  8388609

// ws layout (bytes)
#define WS_SEE   0          // float[1024]
#define WS_SXX   4096       // float[32768]            -> 135168
#define WS_KEY   135168     // u64[32768]              -> 397312
#define WS_LOSS  397312     // double
#define WS_ET    397440     // eT[c][k] float[256][1024] = 1 MB (64B-aligned)

#define FLT_BIG  3.402823466e+38f

// numpy pairwise_sum of 256 squared elements, bit-exact (see round-2 notes).
__device__ __forceinline__ float np_sumsq256(const float* __restrict__ p, int stride) {
    float s[2];
#pragma unroll
    for (int half = 0; half < 2; half++) {
        const float* a = p + half * 128 * stride;
        float r[8];
#pragma unroll
        for (int l = 0; l < 8; l++) {
            float v = a[l * stride];
            float sq = v * v;
            asm volatile("" : "+v"(sq));   // forbid fma contraction into the add chain
            r[l] = sq;
        }
#pragma unroll
        for (int i = 8; i < 128; i += 8) {
#pragma unroll
            for (int l = 0; l < 8; l++) {
                float v = a[(i + l) * stride];
                float sq = v * v;
                asm volatile("" : "+v"(sq));
                r[l] = r[l] + sq;
            }
        }
        s[half] = ((r[0] + r[1]) + (r[2] + r[3])) + ((r[4] + r[5]) + (r[6] + r[7]));
    }
    return s[0] + s[1];
}

__device__ __forceinline__ unsigned int f32_sortable(float m) {
    unsigned int u = __float_as_uint(m);
    return u ^ (((unsigned int)((int)u >> 31)) | 0x80000000u);
}

// ---------------- k0: codebook ||e||^2 (np semantics) + init ----------------
__global__ __launch_bounds__(256) void k0_see(const float* __restrict__ emb,
                                              float* __restrict__ see,
                                              double* __restrict__ loss) {
    const int k = blockIdx.x * 256 + threadIdx.x;   // grid 4 x 256
    see[k] = np_sumsq256(emb + (size_t)k * 256, 1);
    if (k == 0) { *loss = 0.0; }
}

// ---------------- k_et: transpose codebook -> eT[c][k] ----------------
// grid 64 x 256: block handles 16 codes x all 256 c.
__global__ __launch_bounds__(256) void k_et(const float* __restrict__ emb,
                                            float* __restrict__ eT) {
    __shared__ float T[256][17];
    const int t  = threadIdx.x;
    const int k0 = blockIdx.x << 4;
    const int kr = t >> 4, cs = (t & 15) << 4;
#pragma unroll
    for (int j = 0; j < 4; j++) {
        const float4 v = *(const float4*)(emb + (size_t)(k0 + kr) * 256 + cs + j * 4);
        T[cs + j * 4 + 0][kr] = v.x;
        T[cs + j * 4 + 1][kr] = v.y;
        T[cs + j * 4 + 2][kr] = v.z;
        T[cs + j * 4 + 3][kr] = v.w;
    }
    __syncthreads();
    float* dst = eT + (size_t)t * 1024 + k0;   // row c = t, 16 consecutive codes
#pragma unroll
    for (int j = 0; j < 4; j++) {
        float4 v;
        v.x = T[t][j * 4 + 0]; v.y = T[t][j * 4 + 1];
        v.z = T[t][j * 4 + 2]; v.w = T[t][j * 4 + 3];
        *(float4*)(dst + j * 4) = v;
    }
}

// ---------------- k_sxx: per-row ||x||^2 (np semantics) + key init ----------------
__global__ __launch_bounds__(64) void k_sxx(const float* __restrict__ x,
                                            float* __restrict__ sxx,
                                            unsigned long long* __restrict__ key) {
    const int n = blockIdx.x * 64 + threadIdx.x;    // grid 512 x 64
    const int b = n >> 10, hw = n & 1023;
    sxx[n] = np_sumsq256(x + (size_t)b * 262144 + hw, 1024);
    key[n] = ~0ull;
}

// ---------------- k1: SGPR-B distance + argmin ----------------
// grid 4096 (= 512 row-sets x 8 code-blocks), block 256 threads (4 waves).
// Wave: 64 rows (one per lane) x 32 codes (wave-uniform -> SGPR b operands).
// Per c-step: 1 coalesced global_load_dword (a), 128 B uniform s_load (b),
// 32 v_fma_f32 (SGPR operand) = 64 cyc VALU per load. No LDS in hot loop.
// unroll 8: compiler batches 8 a-loads + b s_loads per body with counted
// waitcnts (its native scheduling strength) -- no manual rotation movs.
// dot = sequential fp32 FMA chain over c=0..255 (dependent chain, no
// fast-math => compiler cannot reassociate; bit-matches np reference).
__global__ __launch_bounds__(256) void k1_dist(const float* __restrict__ x,
                                               const float* __restrict__ eT,
                                               const float* __restrict__ see_g,
                                               const float* __restrict__ sxx_g,
                                               unsigned long long* __restrict__ key) {
    const int t  = threadIdx.x;
    const int l  = t & 63;
    const int wv = __builtin_amdgcn_readfirstlane(t >> 6);   // 0..3, uniform
    const int bid = blockIdx.x;
    const int rs  = bid >> 3;                 // row-set (64 rows)
    const int q   = bid & 7;                  // code-block (128 codes)
    const int k0  = q * 128 + wv * 32;        // wave's 32 codes (uniform)
    const int b   = rs >> 4;
    const int hw0 = (rs & 15) << 6;
    const int n   = rs * 64 + l;

    const float* __restrict__ xc = x  + (size_t)b * 262144 + hw0 + l;  // +1024/c
    const float* __restrict__ ec = eT + k0;                            // +1024/c

    float acc[32];
#pragma unroll
    for (int j = 0; j < 32; j++) acc[j] = 0.f;

#pragma unroll 8
    for (int c = 0; c < 256; ++c) {
        const float a = xc[(size_t)c << 10];
#pragma unroll
        for (int j = 0; j < 32; ++j)
            acc[j] = fmaf(a, ec[((size_t)c << 10) + j], acc[j]);
    }

    // fold: q = fl(fl(sxx - 2*dot) + see); packed (sortable(q),k) min ==
    // min distance then lowest index == numpy first-occurrence argmin.
    const float sx = sxx_g[n];
    unsigned long long best = ~0ull;
#pragma unroll
    for (int j = 0; j < 32; j++) {
        const float t1 = fmaf(-2.f, acc[j], sx);
        const float qd = t1 + see_g[k0 + j];
        const unsigned long long pk =
            ((unsigned long long)f32_sortable(qd) << 32) | (unsigned int)(k0 + j);
        best = pk < best ? pk : best;
    }

    // in-block reduce (4 waves) then one atomicMin per row per block
    __shared__ unsigned long long red[4][64];
    red[wv][l] = best;
    __syncthreads();
    if (t < 64) {
        unsigned long long m = red[0][t];
        m = red[1][t] < m ? red[1][t] : m;
        m = red[2][t] < m ? red[2][t] : m;
        m = red[3][t] < m ? red[3][t] : m;
        atomicMin(&key[rs * 64 + t], m);
    }
}

// ---------------- k3: gather quantized + loss partials + indices ----------------
__global__ __launch_bounds__(256) void k3_out(const float* __restrict__ x,
                                              const float* __restrict__ emb,
                                              const unsigned long long* __restrict__ key,
                                              float* __restrict__ dout,
                                              double* __restrict__ loss) {
    __shared__ float elds[32][257];
    __shared__ int   idxs[32];
    __shared__ float red[256];
    const int t  = threadIdx.x;
    const int bh = blockIdx.x;
    const int b = bh >> 5, h = bh & 31;
    if (t < 32) idxs[t] = (int)(key[(bh << 5) + t] & 0xffffffffull);
    __syncthreads();
    for (int r = 0; r < 32; r++) elds[r][t] = emb[(size_t)idxs[r] * 256 + t];
    __syncthreads();
    const int w = t & 31, cg = t >> 5;
    const size_t base = (size_t)b * 262144 + (size_t)(h * 32 + w);
    float acc = 0.f;
#pragma unroll 4
    for (int s = 0; s < 32; s++) {
        const int c = (cg << 5) + s;
        const float q  = elds[w][c];
        const float xv = x[base + (size_t)c * 1024];
        dout[base + (size_t)c * 1024] = q;
        const float d = q - xv;
        acc = fmaf(d, d, acc);
    }
    red[t] = acc;
    __syncthreads();
    for (int s = 128; s > 0; s >>= 1) {
        if (t < s) red[t] += red[t + s];
        __syncthreads();
    }
    if (t == 0) atomicAdd(loss, (double)red[0]);
    if (t < 32) dout[IDX_OFF + (bh << 5) + t] = (float)idxs[t];
}

// ---------------- k4: finalize loss ----------------
__global__ void k4_fin(const double* __restrict__ loss, float* __restrict__ dout) {
    dout[LOSS_OFF] = (float)(1.25 * (*loss) / 8388608.0);
}

extern "C" void kernel_launch(void* const* d_in, const int* in_sizes, int n_in,
                              void* d_out, int out_size, void* d_ws, size_t ws_size,
                              hipStream_t stream) {
    const float* x   = (const float*)d_in[0];
    const float* emb = (const float*)d_in[1];
    float* dout = (float*)d_out;
    char* ws = (char*)d_ws;
    float*  see  = (float*)(ws + WS_SEE);
    float*  sxx  = (float*)(ws + WS_SXX);
    unsigned long long* key = (unsigned long long*)(ws + WS_KEY);
    double* loss = (double*)(ws + WS_LOSS);
    float*  eT   = (float*)(ws + WS_ET);

    k0_see<<<4, 256, 0, stream>>>(emb, see, loss);
    k_et<<<64, 256, 0, stream>>>(emb, eT);
    k_sxx<<<512, 64, 0, stream>>>(x, sxx, key);
    k1_dist<<<4096, 256, 0, stream>>>(x, eT, see, sxx, key);
    k3_out<<<1024, 256, 0, stream>>>(x, emb, key, dout, loss);
    k4_fin<<<1, 1, 0, stream>>>(loss, dout);
}